// Round 11
// baseline (108.470 us; speedup 1.0000x reference)
//
#include <hip/hip_runtime.h>
#include <stdint.h>

// ConformerSelfAttention (B=8,T=1024,D=512,H=8,DK=64) for gfx950. Round 11.
// gemm: 4-buffer BK=32 counted-vmcnt pipeline (raw s_barrier, never drain to 0
// mid-loop), 64B-row XOR-swizzled LDS. attn: R9 body (best measured).

typedef __attribute__((ext_vector_type(8))) short s8v;
typedef __attribute__((ext_vector_type(4))) short s4v;
typedef __attribute__((ext_vector_type(4))) float f4v;
typedef unsigned short u16;

#define MFMA(a, b, c) __builtin_amdgcn_mfma_f32_16x16x32_bf16((a), (b), (c), 0, 0, 0)

__device__ __forceinline__ float bf2f(u16 u) {
    union { unsigned i; float f; } w; w.i = ((unsigned)u) << 16; return w.f;
}
__device__ __forceinline__ u16 f2bf(float f) {   // RTNE (outputs)
    union { float f; unsigned i; } w; w.f = f;
    return (u16)((w.i + 0x7FFFu + ((w.i >> 16) & 1u)) >> 16);
}
__device__ __forceinline__ u16 f2bt(float f) {   // trunc (intermediates)
    union { float f; unsigned i; } w; w.f = f;
    return (u16)(w.i >> 16);
}
__device__ __forceinline__ void gld16(const void* g, void* l) {
    __builtin_amdgcn_global_load_lds(
        (const __attribute__((address_space(1))) unsigned int*)g,
        (__attribute__((address_space(3))) unsigned int*)l, 16, 0, 0);
}

// ------------- prep (W^T->bf16, pos_emb->bf16, xlens tail) + LayerNorm, merged -------------
__global__ __launch_bounds__(256) void prep_k(
    const float* __restrict__ Wq, const float* __restrict__ Wk, const float* __restrict__ Wv,
    const float* __restrict__ Wpos, const float* __restrict__ Wo,
    const float* __restrict__ pos_emb, const int* __restrict__ xlens,
    const float* __restrict__ x, const float* __restrict__ gamma,
    const float* __restrict__ beta,
    u16* __restrict__ wt, u16* __restrict__ pe, float* __restrict__ tail,
    u16* __restrict__ xn)
{
    int bid = blockIdx.x, tid = threadIdx.x;
    if (bid < 1280) {
        __shared__ float lt[32][33];
        int mat = bid >> 8, tile = bid & 255;
        int kt = (tile >> 4) << 5, nt = (tile & 15) << 5;
        const float* W = mat == 0 ? Wq : mat == 1 ? Wk : mat == 2 ? Wv : mat == 3 ? Wpos : Wo;
        int ty = tid >> 3, tx = tid & 7;
        float4 vv = *(const float4*)&W[(kt + ty) * 512 + nt + tx * 4];
        lt[ty][tx * 4 + 0] = vv.x; lt[ty][tx * 4 + 1] = vv.y;
        lt[ty][tx * 4 + 2] = vv.z; lt[ty][tx * 4 + 3] = vv.w;
        __syncthreads();
        int nl = tid >> 3, k4 = (tid & 7) * 4;
        union { s4v v; u16 u[4]; } ob;
        #pragma unroll
        for (int e = 0; e < 4; ++e) ob.u[e] = f2bf(lt[k4 + e][nl]);
        *(s4v*)&wt[mat * 262144 + (nt + nl) * 512 + kt + k4] = ob.v;
    } else if (bid < 2304) {
        int i = (bid - 1280) * 1024 + tid * 4;
        union { s4v v; u16 u[4]; } ob;
        if (i < 2047 * 512) {
            float4 vv = *(const float4*)&pos_emb[i];
            ob.u[0] = f2bf(vv.x); ob.u[1] = f2bf(vv.y);
            ob.u[2] = f2bf(vv.z); ob.u[3] = f2bf(vv.w);
        } else {
            ob.u[0] = ob.u[1] = ob.u[2] = ob.u[3] = 0;
        }
        *(s4v*)&pe[i] = ob.v;
    } else if (bid == 2304) {
        if (tid < 8) tail[tid] = (float)xlens[tid];
    } else {
        int tok = (bid - 2305) * 4 + (tid >> 6);
        int l = tid & 63;
        const float* xr = x + (size_t)tok * 512 + l * 8;
        float v[8];
        {
            float4 a = *(const float4*)xr; float4 b = *(const float4*)(xr + 4);
            v[0] = a.x; v[1] = a.y; v[2] = a.z; v[3] = a.w;
            v[4] = b.x; v[5] = b.y; v[6] = b.z; v[7] = b.w;
        }
        float s = 0.f, q = 0.f;
        #pragma unroll
        for (int e = 0; e < 8; ++e) { s += v[e]; q += v[e] * v[e]; }
        #pragma unroll
        for (int off = 1; off < 64; off <<= 1) { s += __shfl_xor(s, off); q += __shfl_xor(q, off); }
        float mean = s * (1.f / 512.f);
        float var = q * (1.f / 512.f) - mean * mean;
        float inv = rsqrtf(var + 1e-5f);
        union { s8v v; u16 u[8]; } ob;
        #pragma unroll
        for (int e = 0; e < 8; ++e)
            ob.u[e] = f2bf((v[e] - mean) * inv * gamma[l * 8 + e] + beta[l * 8 + e]);
        *(s8v*)&xn[(size_t)tok * 512 + l * 8] = ob.v;
    }
}

// ------- GEMM v3: 128x128 tile, BK=32, 4 buffers, counted-vmcnt pipeline -------
// mode 0 grid(64,13): y<12 fused QKV (+bias, per-head; V transposed); y==12: P.
// mode 2 grid(64,4): out = AO @ WoT + bo (fp32).
__global__ __launch_bounds__(256, 2) void gemm_k(
    const u16* __restrict__ A, const u16* __restrict__ Ap, const u16* __restrict__ wt,
    const float* __restrict__ bq, const float* __restrict__ bk, const float* __restrict__ bv,
    int mode, u16* __restrict__ qo, u16* __restrict__ ko, u16* __restrict__ vtg,
    u16* __restrict__ pb, float* __restrict__ of)
{
    __shared__ u16 Al[4][128 * 32];
    __shared__ u16 Bl[4][128 * 32];
    int tid = threadIdx.x, l = tid & 63, wid = tid >> 6;
    int wr = wid >> 1, wc = wid & 1, r = l & 15, g = l >> 4;
    int m0, nb, mat;
    const u16 *Ag, *Wg;
    if (mode == 0) {
        if (blockIdx.y < 12) {
            m0 = blockIdx.x << 7; int n0 = blockIdx.y << 7;
            mat = n0 >> 9; nb = n0 & 511; Ag = A; Wg = wt + mat * 262144;
        } else {
            mat = 3; m0 = (blockIdx.x & 15) << 7; nb = (blockIdx.x >> 4) << 7;
            Ag = Ap; Wg = wt + 3 * 262144;
        }
    } else {
        mat = 4; m0 = blockIdx.x << 7; nb = blockIdx.y << 7; Ag = A; Wg = wt + 4 * 262144;
    }

    int sr4 = l >> 2;                                        // row in 16-row group
    int csw2 = (((l & 3) ^ ((l >> 2) & 3) ^ (l >> 4)) << 3); // pre-swz src col
    int offK = ((g ^ ((r & 3) ^ (r >> 2))) << 3);            // swz read col

    f4v zero = {0.f, 0.f, 0.f, 0.f};
    f4v acc[4][4];
    #pragma unroll
    for (int i = 0; i < 4; ++i)
        #pragma unroll
        for (int j = 0; j < 4; ++j) acc[i][j] = zero;

    // prologue: stage k-tiles 0..2 into buffers 0..2 (12 loads/thread in flight)
    #pragma unroll
    for (int t = 0; t < 3; ++t) {
        #pragma unroll
        for (int it = 0; it < 2; ++it) {
            int rowb = wid * 32 + it * 16;
            gld16(&Ag[(size_t)(m0 + rowb + sr4) * 512 + t * 32 + csw2], &Al[t][rowb * 32]);
            gld16(&Wg[(size_t)(nb + rowb + sr4) * 512 + t * 32 + csw2], &Bl[t][rowb * 32]);
        }
    }

    for (int t = 0; t < 16; ++t) {
        int buf = t & 3;
        // own stage(t) landed; keep 2 buffers (8 loads) in flight
        if (t < 14)       asm volatile("s_waitcnt vmcnt(8)" ::: "memory");
        else if (t == 14) asm volatile("s_waitcnt vmcnt(4)" ::: "memory");
        else              asm volatile("s_waitcnt vmcnt(0)" ::: "memory");
        __builtin_amdgcn_s_barrier();          // raw: no vmcnt(0) drain
        asm volatile("" ::: "memory");
        s8v af[4], bfv[4];
        #pragma unroll
        for (int i = 0; i < 4; ++i)
            af[i] = *(const s8v*)&Al[buf][(wr * 64 + i * 16 + r) * 32 + offK];
        #pragma unroll
        for (int j = 0; j < 4; ++j)
            bfv[j] = *(const s8v*)&Bl[buf][(wc * 64 + j * 16 + r) * 32 + offK];
        __builtin_amdgcn_s_setprio(1);
        #pragma unroll
        for (int i = 0; i < 4; ++i)
            #pragma unroll
            for (int j = 0; j < 4; ++j)
                acc[i][j] = MFMA(af[i], bfv[j], acc[i][j]);
        __builtin_amdgcn_s_setprio(0);
        // issue stage(t+3) into buffer (t+3)&3 (read at iter t-1, all waves past it)
        if (t + 3 < 16) {
            int k1 = (t + 3) << 5, nbuf = (t + 3) & 3;
            #pragma unroll
            for (int it = 0; it < 2; ++it) {
                int rowb = wid * 32 + it * 16;
                gld16(&Ag[(size_t)(m0 + rowb + sr4) * 512 + k1 + csw2], &Al[nbuf][rowb * 32]);
                gld16(&Wg[(size_t)(nb + rowb + sr4) * 512 + k1 + csw2], &Bl[nbuf][rowb * 32]);
            }
        }
    }

    #pragma unroll
    for (int i = 0; i < 4; ++i)
        #pragma unroll
        for (int j = 0; j < 4; ++j) {
            int ncol = nb + wc * 64 + j * 16 + r;
            int mbase = m0 + wr * 64 + i * 16 + g * 4;
            if (mode == 2) {
                float bb = bq[ncol];
                #pragma unroll
                for (int jj = 0; jj < 4; ++jj)
                    of[(size_t)(mbase + jj) * 512 + ncol] = acc[i][j][jj] + bb;
            } else if (mat == 3) {
                int hh = ncol >> 6, dk = ncol & 63;
                #pragma unroll
                for (int jj = 0; jj < 4; ++jj) {
                    int m = mbase + jj;
                    if (m < 2047) pb[(hh * 2047 + m) * 64 + dk] = f2bf(acc[i][j][jj]);
                }
            } else if (mat == 2) {
                float bb = bv[ncol];
                int hh = ncol >> 6, dk = ncol & 63;
                int bbx = mbase >> 10, t = mbase & 1023;
                union { s4v v; u16 u[4]; } pk;
                #pragma unroll
                for (int jj = 0; jj < 4; ++jj) pk.u[jj] = f2bf(acc[i][j][jj] + bb);
                *(s4v*)&vtg[((size_t)(bbx * 8 + hh) * 64 + dk) * 1024 + t] = pk.v;
            } else {
                float bb = (mat == 0 ? bq : bk)[ncol];
                u16* dst = (mat == 0) ? qo : ko;
                int hh = ncol >> 6, dk = ncol & 63;
                #pragma unroll
                for (int jj = 0; jj < 4; ++jj) {
                    int m = mbase + jj;
                    int bbx = m >> 10, t = m & 1023;
                    dst[((size_t)(bbx * 8 + hh) * 1024 + t) * 64 + dk] = f2bf(acc[i][j][jj] + bb);
                }
            }
        }
}

// ---------------- flash rel-pos attention (R9 body: 8 waves x 16 rows) ----------------
__global__ __launch_bounds__(512, 4) void attn_k(
    const u16* __restrict__ q, const u16* __restrict__ k, const u16* __restrict__ vtg,
    const u16* __restrict__ p, const float* __restrict__ pbu, const float* __restrict__ pbv,
    const int* __restrict__ xlens, u16* __restrict__ ao)
{
    __shared__ u16 Ks[2][64 * 64];
    __shared__ u16 Vt[64 * 64];
    __shared__ u16 Ps[256 * 64];
    __shared__ u16 Tb[8][16 * 72];

    int tid = threadIdx.x, l = tid & 63, wid = tid >> 6;   // wid 0..7
    int r = l & 15, g = l >> 4, kq = g << 3;
    int t0 = blockIdx.x << 7;
    int bh = blockIdx.y, b = bh & 7, h = bh >> 3;
    int tw = t0 + wid * 16;
    int xlen = xlens[b];
    const u16* qh = q + (size_t)(b * 8 + h) * 65536;
    const u16* kh = k + (size_t)(b * 8 + h) * 65536;
    const u16* vh = vtg + (size_t)(b * 8 + h) * 65536;
    const u16* ph = p + (size_t)h * 2047 * 64;

    int rw8 = l >> 3;
    int csw = ((l & 7) ^ rw8) << 3;            // pre-swizzled source col (elems)
    int off0 = ((g ^ (r & 7)) << 3);           // swizzled read col, blk g
    int off1 = (((4 + g) ^ (r & 7)) << 3);     // blk 4+g

    const float SCALE = 0.18033688f;           // 0.125 / ln(2)

    // Q frags (+pos biases, prescaled)
    s8v qu[2], qv[2];
    #pragma unroll
    for (int ks = 0; ks < 2; ++ks) {
        union { s8v v; u16 u[8]; } src, du, dv;
        src.v = *(const s8v*)&qh[(tw + r) * 64 + ks * 32 + kq];
        float4 u0 = *(const float4*)&pbu[h * 64 + ks * 32 + kq];
        float4 u1 = *(const float4*)&pbu[h * 64 + ks * 32 + kq + 4];
        float4 v0 = *(const float4*)&pbv[h * 64 + ks * 32 + kq];
        float4 v1 = *(const float4*)&pbv[h * 64 + ks * 32 + kq + 4];
        float ub[8] = {u0.x, u0.y, u0.z, u0.w, u1.x, u1.y, u1.z, u1.w};
        float vb_[8] = {v0.x, v0.y, v0.z, v0.w, v1.x, v1.y, v1.z, v1.w};
        #pragma unroll
        for (int e = 0; e < 8; ++e) {
            float qf = bf2f(src.u[e]);
            du.u[e] = f2bf((qf + ub[e]) * SCALE);
            dv.u[e] = f2bf((qf + vb_[e]) * SCALE);
        }
        qu[ks] = du.v; qv[ks] = dv.v;
    }

    int B0 = 896 - t0;                          // lowest p-row this block touches
    int nst = (xlen + 63) >> 6;

    // ---- prologue: K0, V0 (1 gld/wave), P rows [B0, B0+192) (3 gld/wave) ----
    {
        int rowb = wid * 8;
        gld16(&kh[(rowb + rw8) * 64 + csw], &Ks[0][rowb * 64]);
        gld16(&vh[(rowb + rw8) * 1024 + csw], &Vt[rowb * 64]);
    }
    #pragma unroll
    for (int it = 0; it < 3; ++it) {
        int row = wid * 24 + it * 8;
        int slot = (B0 + row) & 255;
        gld16(&ph[(size_t)(B0 + row + rw8) * 64 + csw], &Ps[slot * 64]);
    }
    __syncthreads();

    float lst[4] = {0.f, 0.f, 0.f, 0.f};
    f4v zero = {0.f, 0.f, 0.f, 0.f};
    f4v o[4] = {zero, zero, zero, zero};
    u16* tb = &Tb[wid][0];

    for (int i = 0; i < nst; ++i) {
        int cur = i & 1, s0 = i << 6;
        // ---- issue V(i) ----
        if (i > 0) {
            int rowb = wid * 8;
            gld16(&vh[(rowb + rw8) * 1024 + s0 + csw], &Vt[rowb * 64]);
        }
        // ---- prefetch K(i+1), P(+64) ----
        if (i + 1 < nst) {
            int s1 = s0 + 64;
            int rowb = wid * 8;
            gld16(&kh[(s1 + rowb + rw8) * 64 + csw], &Ks[cur ^ 1][rowb * 64]);
            int chunk = B0 + 192 + s0 + wid * 8;
            int slot = chunk & 255;
            int gp = chunk + rw8; gp = gp > 2046 ? 2046 : gp;
            gld16(&ph[(size_t)gp * 64 + csw], &Ps[slot * 64]);
        }
        // ---- QK: 8 MFMAs ----
        const u16* KB = &Ks[cur][0];
        f4v st4[4];
        __builtin_amdgcn_s_setprio(1);
        #pragma unroll
        for (int nf = 0; nf < 4; ++nf) {
            int row = (nf * 16 + r) * 64;
            s8v k0 = *(const s8v*)&KB[row + off0];
            s8v k1 = *(const s8v*)&KB[row + off1];
            st4[nf] = MFMA(qu[1], k1, MFMA(qu[0], k0, zero));
        }
        // ---- band: 10 MFMAs ----
        int pstart = 1008 + s0 - tw;
        f4v bst[5];
        #pragma unroll
        for (int pf = 0; pf < 5; ++pf) {
            int slot = (pstart + pf * 16 + r) & 255;
            const u16* rowp = &Ps[slot * 64];
            f4v a = MFMA(qv[0], *(const s8v*)&rowp[off0], zero);
            bst[pf] = MFMA(qv[1], *(const s8v*)&rowp[off1], a);
        }
        __builtin_amdgcn_s_setprio(0);
        bool full = (s0 + 64 <= xlen);
        // ---- packed 3-bperm rel-shift gather + exp2 ----
        float pr[4][4];
        #pragma unroll
        for (int j = 0; j < 4; ++j) {
            int tl = g * 4 + j;
            int d = r + 15 - tl;                       // 0..30
            int al = ((g << 4) | (d & 15)) << 2;
            unsigned w0 = (unsigned)f2bt(bst[0][j]) | ((unsigned)f2bt(bst[1][j]) << 16);
            unsigned w1 = (unsigned)f2bt(bst[2][j]) | ((unsigned)f2bt(bst[3][j]) << 16);
            unsigned w2 = (unsigned)f2bt(bst[4][j]);
            unsigned p0 = (unsigned)__builtin_amdgcn_ds_bpermute(al, (int)w0);
            unsigned p1 = (unsigned)__builtin_amdgcn_ds_bpermute(al, (int)w1);
            unsigned p2 = (unsigned)__builtin_amdgcn_ds_bpermute(al, (int)w2);
            bool lo = d < 16;
            float bds[4];
            bds[0] = bf2f((u16)(lo ? (p0 & 0xffffu) : (p0 >> 16)));
            bds[1] = bf2f((u16)(lo ? (p0 >> 16) : (p1 & 0xffffu)));
            bds[2] = bf2f((u16)(lo ? (p1 & 0xffffu) : (p1 >> 16)));
            bds[3] = bf2f((u16)(lo ? (p1 >> 16) : (p2 & 0xffffu)));
            #pragma unroll
            for (int nf = 0; nf < 4; ++nf) {
                float e = exp2f(st4[nf][j] + bds[nf]);
                if (!full) e = (s0 + nf * 16 + r >= xlen) ? 0.f : e;
                pr[nf][j] = e;
            }
        }
        #pragma unroll
        for (int j = 0; j < 4; ++j)
            lst[j] += (pr[0][j] + pr[1][j]) + (pr[2][j] + pr[3][j]);
        // ---- P -> per-wave LDS A-tile, read back frags ----
        #pragma unroll
        for (int nf = 0; nf < 4; ++nf)
            #pragma unroll
            for (int j = 0; j < 4; ++j)
                tb[(g * 4 + j) * 72 + nf * 16 + r] = f2bt(pr[nf][j]);
        asm volatile("s_waitcnt lgkmcnt(0)" ::: "memory");
        __builtin_amdgcn_sched_barrier(0);
        s8v pa0 = *(const s8v*)&tb[r * 72 + kq];
        s8v pa1 = *(const s8v*)&tb[r * 72 + 32 + kq];
        // ---- wait V (counted: keep K/P prefetch in flight) ----
        if (i > 0) {
            if (i + 1 < nst) asm volatile("s_waitcnt vmcnt(2)" ::: "memory");
            else             asm volatile("s_waitcnt vmcnt(0)" ::: "memory");
        }
        // ---- PV: 8 MFMAs ----
        __builtin_amdgcn_s_setprio(1);
        #pragma unroll
        for (int i2 = 0; i2 < 4; ++i2) {
            int vrow = (i2 * 16 + r) * 64;
            o[i2] = MFMA(pa0, *(const s8v*)&Vt[vrow + off0], o[i2]);
            o[i2] = MFMA(pa1, *(const s8v*)&Vt[vrow + off1], o[i2]);
        }
        __builtin_amdgcn_s_setprio(0);
        __syncthreads();
    }
    // ---- final l reduce + normalize + write ----
    #pragma unroll
    for (int j = 0; j < 4; ++j) {
        float rs = lst[j];
        rs += __shfl_xor(rs, 1); rs += __shfl_xor(rs, 2);
        rs += __shfl_xor(rs, 4); rs += __shfl_xor(rs, 8);
        float inv = 1.f / rs;
        int t = tw + g * 4 + j;
        #pragma unroll
        for (int i2 = 0; i2 < 4; ++i2)
            ao[((size_t)(b * 1024 + t)) * 512 + h * 64 + i2 * 16 + r] = f2bf(o[i2][j] * inv);
    }
}

// ---------------- launch ----------------
extern "C" void kernel_launch(void* const* d_in, const int* in_sizes, int n_in,
                              void* d_out, int out_size, void* d_ws, size_t ws_size,
                              hipStream_t stream)
{
    (void)in_sizes; (void)n_in; (void)out_size; (void)ws_size;
    const float* x     = (const float*)d_in[0];
    const int*   xlens = (const int*)d_in[1];
    const float* pos_e = (const float*)d_in[2];
    const float* gam   = (const float*)d_in[3];
    const float* bet   = (const float*)d_in[4];
    const float* Wq    = (const float*)d_in[5];
    const float* bq    = (const float*)d_in[6];
    const float* Wk    = (const float*)d_in[7];
    const float* bk    = (const float*)d_in[8];
    const float* Wv    = (const float*)d_in[9];
    const float* bv    = (const float*)d_in[10];
    const float* Wpos  = (const float*)d_in[11];
    const float* pbu   = (const float*)d_in[12];
    const float* pbv   = (const float*)d_in[13];
    const float* Wo    = (const float*)d_in[14];
    const float* bo    = (const float*)d_in[15];
    float* out = (float*)d_out;

    char* ws = (char*)d_ws;
    u16* xn  = (u16*)(ws);                    // LN out, later attn out
    u16* qb  = (u16*)(ws + 8388608);          // (B,H,T,DK)
    u16* kb  = (u16*)(ws + 16777216);         // (B,H,T,DK)
    u16* vtg = (u16*)(ws + 25165824);         // (B,H,DK,T) transposed
    u16* pbf = (u16*)(ws + 33554432);         // (H,2047,DK)
    u16* pe  = (u16*)(ws + 35651584);         // pos_emb bf16, 2048 rows
    u16* wt  = (u16*)(ws + 37748736);         // 5 x 512x512 W^T bf16

    prep_k<<<4353, 256, 0, stream>>>(Wq, Wk, Wv, Wpos, Wo, pos_e, xlens,
                                     x, gam, bet, wt, pe,
                                     out + (size_t)8192 * 512, xn);
    gemm_k<<<dim3(64, 13), 256, 0, stream>>>(xn, pe, wt, bq, bk, bv, 0,
                                             qb, kb, vtg, pbf, nullptr);
    attn_k<<<dim3(8, 64), 512, 0, stream>>>(qb, kb, vtg, pbf, pbu, pbv, xlens, xn);
    gemm_k<<<dim3(64, 4), 256, 0, stream>>>(xn, nullptr, wt, bo, nullptr, nullptr, 2,
                                            nullptr, nullptr, nullptr, nullptr, out);
}

// Round 12
// 101.893 us; speedup vs baseline: 1.0646x; 1.0646x over previous
//
#include <hip/hip_runtime.h>
#include <stdint.h>

// ConformerSelfAttention (B=8,T=1024,D=512,H=8,DK=64) for gfx950. Round 12.
// Revert to R9 exactly — best measured configuration (102.3 us):
// prep+LN merged; GEMM v2 (128x128, BK=64, stage-ahead dbuf, swizzled LDS);
// attn v9 (8 waves x 16 rows, 512 threads, packed 3-bperm gather).

typedef __attribute__((ext_vector_type(8))) short s8v;
typedef __attribute__((ext_vector_type(4))) short s4v;
typedef __attribute__((ext_vector_type(4))) float f4v;
typedef unsigned short u16;

#define MFMA(a, b, c) __builtin_amdgcn_mfma_f32_16x16x32_bf16((a), (b), (c), 0, 0, 0)

__device__ __forceinline__ float bf2f(u16 u) {
    union { unsigned i; float f; } w; w.i = ((unsigned)u) << 16; return w.f;
}
__device__ __forceinline__ u16 f2bf(float f) {   // RTNE (outputs)
    union { float f; unsigned i; } w; w.f = f;
    return (u16)((w.i + 0x7FFFu + ((w.i >> 16) & 1u)) >> 16);
}
__device__ __forceinline__ u16 f2bt(float f) {   // trunc (intermediates)
    union { float f; unsigned i; } w; w.f = f;
    return (u16)(w.i >> 16);
}
__device__ __forceinline__ void gld16(const void* g, void* l) {
    __builtin_amdgcn_global_load_lds(
        (const __attribute__((address_space(1))) unsigned int*)g,
        (__attribute__((address_space(3))) unsigned int*)l, 16, 0, 0);
}

// ------------- prep (W^T->bf16, pos_emb->bf16, xlens tail) + LayerNorm, merged -------------
__global__ __launch_bounds__(256) void prep_k(
    const float* __restrict__ Wq, const float* __restrict__ Wk, const float* __restrict__ Wv,
    const float* __restrict__ Wpos, const float* __restrict__ Wo,
    const float* __restrict__ pos_emb, const int* __restrict__ xlens,
    const float* __restrict__ x, const float* __restrict__ gamma,
    const float* __restrict__ beta,
    u16* __restrict__ wt, u16* __restrict__ pe, float* __restrict__ tail,
    u16* __restrict__ xn)
{
    int bid = blockIdx.x, tid = threadIdx.x;
    if (bid < 1280) {
        __shared__ float lt[32][33];
        int mat = bid >> 8, tile = bid & 255;
        int kt = (tile >> 4) << 5, nt = (tile & 15) << 5;
        const float* W = mat == 0 ? Wq : mat == 1 ? Wk : mat == 2 ? Wv : mat == 3 ? Wpos : Wo;
        int ty = tid >> 3, tx = tid & 7;
        float4 vv = *(const float4*)&W[(kt + ty) * 512 + nt + tx * 4];
        lt[ty][tx * 4 + 0] = vv.x; lt[ty][tx * 4 + 1] = vv.y;
        lt[ty][tx * 4 + 2] = vv.z; lt[ty][tx * 4 + 3] = vv.w;
        __syncthreads();
        int nl = tid >> 3, k4 = (tid & 7) * 4;
        union { s4v v; u16 u[4]; } ob;
        #pragma unroll
        for (int e = 0; e < 4; ++e) ob.u[e] = f2bf(lt[k4 + e][nl]);
        *(s4v*)&wt[mat * 262144 + (nt + nl) * 512 + kt + k4] = ob.v;
    } else if (bid < 2304) {
        int i = (bid - 1280) * 1024 + tid * 4;
        union { s4v v; u16 u[4]; } ob;
        if (i < 2047 * 512) {
            float4 vv = *(const float4*)&pos_emb[i];
            ob.u[0] = f2bf(vv.x); ob.u[1] = f2bf(vv.y);
            ob.u[2] = f2bf(vv.z); ob.u[3] = f2bf(vv.w);
        } else {
            ob.u[0] = ob.u[1] = ob.u[2] = ob.u[3] = 0;
        }
        *(s4v*)&pe[i] = ob.v;
    } else if (bid == 2304) {
        if (tid < 8) tail[tid] = (float)xlens[tid];
    } else {
        int tok = (bid - 2305) * 4 + (tid >> 6);
        int l = tid & 63;
        const float* xr = x + (size_t)tok * 512 + l * 8;
        float v[8];
        {
            float4 a = *(const float4*)xr; float4 b = *(const float4*)(xr + 4);
            v[0] = a.x; v[1] = a.y; v[2] = a.z; v[3] = a.w;
            v[4] = b.x; v[5] = b.y; v[6] = b.z; v[7] = b.w;
        }
        float s = 0.f, q = 0.f;
        #pragma unroll
        for (int e = 0; e < 8; ++e) { s += v[e]; q += v[e] * v[e]; }
        #pragma unroll
        for (int off = 1; off < 64; off <<= 1) { s += __shfl_xor(s, off); q += __shfl_xor(q, off); }
        float mean = s * (1.f / 512.f);
        float var = q * (1.f / 512.f) - mean * mean;
        float inv = rsqrtf(var + 1e-5f);
        union { s8v v; u16 u[8]; } ob;
        #pragma unroll
        for (int e = 0; e < 8; ++e)
            ob.u[e] = f2bf((v[e] - mean) * inv * gamma[l * 8 + e] + beta[l * 8 + e]);
        *(s8v*)&xn[(size_t)tok * 512 + l * 8] = ob.v;
    }
}

// ---------------- GEMM v2: 128x128 tile, BK=64, stage-ahead dbuf, swizzled LDS ----------
__global__ __launch_bounds__(256, 2) void gemm_k(
    const u16* __restrict__ A, const u16* __restrict__ Ap, const u16* __restrict__ wt,
    const float* __restrict__ bq, const float* __restrict__ bk, const float* __restrict__ bv,
    int mode, u16* __restrict__ qo, u16* __restrict__ ko, u16* __restrict__ vtg,
    u16* __restrict__ pb, float* __restrict__ of)
{
    __shared__ u16 Al[2][128 * 64];
    __shared__ u16 Bl[2][128 * 64];
    int tid = threadIdx.x, l = tid & 63, wid = tid >> 6;
    int wr = wid >> 1, wc = wid & 1, r = l & 15, g = l >> 4;
    int m0, nb, mat;
    const u16 *Ag, *Wg;
    if (mode == 0) {
        if (blockIdx.y < 12) {
            m0 = blockIdx.x << 7; int n0 = blockIdx.y << 7;
            mat = n0 >> 9; nb = n0 & 511; Ag = A; Wg = wt + mat * 262144;
        } else {
            mat = 3; m0 = (blockIdx.x & 15) << 7; nb = (blockIdx.x >> 4) << 7;
            Ag = Ap; Wg = wt + 3 * 262144;
        }
    } else {
        mat = 4; m0 = blockIdx.x << 7; nb = blockIdx.y << 7; Ag = A; Wg = wt + 4 * 262144;
    }

    int rw8 = l >> 3;
    int csw = ((l & 7) ^ rw8) << 3;
    int off0 = ((g ^ (r & 7)) << 3);
    int off1 = (((4 + g) ^ (r & 7)) << 3);

    f4v zero = {0.f, 0.f, 0.f, 0.f};
    f4v acc[4][4];
    #pragma unroll
    for (int i = 0; i < 4; ++i)
        #pragma unroll
        for (int j = 0; j < 4; ++j) acc[i][j] = zero;

    #pragma unroll
    for (int it = 0; it < 4; ++it) {
        int rowb = wid * 32 + it * 8;
        gld16(&Ag[(size_t)(m0 + rowb + rw8) * 512 + csw], &Al[0][rowb * 64]);
        gld16(&Wg[(size_t)(nb + rowb + rw8) * 512 + csw], &Bl[0][rowb * 64]);
    }
    __syncthreads();

    for (int t = 0; t < 8; ++t) {
        int cur = t & 1;
        if (t < 7) {
            int k1 = (t + 1) << 6;
            #pragma unroll
            for (int it = 0; it < 4; ++it) {
                int rowb = wid * 32 + it * 8;
                gld16(&Ag[(size_t)(m0 + rowb + rw8) * 512 + k1 + csw], &Al[cur ^ 1][rowb * 64]);
                gld16(&Wg[(size_t)(nb + rowb + rw8) * 512 + k1 + csw], &Bl[cur ^ 1][rowb * 64]);
            }
        }
        s8v af[4][2], bfv[4][2];
        #pragma unroll
        for (int i = 0; i < 4; ++i) {
            int row = (wr * 64 + i * 16 + r) * 64;
            af[i][0] = *(const s8v*)&Al[cur][row + off0];
            af[i][1] = *(const s8v*)&Al[cur][row + off1];
        }
        #pragma unroll
        for (int j = 0; j < 4; ++j) {
            int row = (wc * 64 + j * 16 + r) * 64;
            bfv[j][0] = *(const s8v*)&Bl[cur][row + off0];
            bfv[j][1] = *(const s8v*)&Bl[cur][row + off1];
        }
        __builtin_amdgcn_s_setprio(1);
        #pragma unroll
        for (int i = 0; i < 4; ++i)
            #pragma unroll
            for (int j = 0; j < 4; ++j) {
                acc[i][j] = MFMA(af[i][0], bfv[j][0], acc[i][j]);
                acc[i][j] = MFMA(af[i][1], bfv[j][1], acc[i][j]);
            }
        __builtin_amdgcn_s_setprio(0);
        __syncthreads();
    }

    #pragma unroll
    for (int i = 0; i < 4; ++i)
        #pragma unroll
        for (int j = 0; j < 4; ++j) {
            int ncol = nb + wc * 64 + j * 16 + r;
            int mbase = m0 + wr * 64 + i * 16 + g * 4;
            if (mode == 2) {
                float bb = bq[ncol];
                #pragma unroll
                for (int jj = 0; jj < 4; ++jj)
                    of[(size_t)(mbase + jj) * 512 + ncol] = acc[i][j][jj] + bb;
            } else if (mat == 3) {
                int hh = ncol >> 6, dk = ncol & 63;
                #pragma unroll
                for (int jj = 0; jj < 4; ++jj) {
                    int m = mbase + jj;
                    if (m < 2047) pb[(hh * 2047 + m) * 64 + dk] = f2bf(acc[i][j][jj]);
                }
            } else if (mat == 2) {
                float bb = bv[ncol];
                int hh = ncol >> 6, dk = ncol & 63;
                int bbx = mbase >> 10, t = mbase & 1023;
                union { s4v v; u16 u[4]; } pk;
                #pragma unroll
                for (int jj = 0; jj < 4; ++jj) pk.u[jj] = f2bf(acc[i][j][jj] + bb);
                *(s4v*)&vtg[((size_t)(bbx * 8 + hh) * 64 + dk) * 1024 + t] = pk.v;
            } else {
                float bb = (mat == 0 ? bq : bk)[ncol];
                u16* dst = (mat == 0) ? qo : ko;
                int hh = ncol >> 6, dk = ncol & 63;
                #pragma unroll
                for (int jj = 0; jj < 4; ++jj) {
                    int m = mbase + jj;
                    int bbx = m >> 10, t = m & 1023;
                    dst[((size_t)(bbx * 8 + hh) * 1024 + t) * 64 + dk] = f2bf(acc[i][j][jj] + bb);
                }
            }
        }
}

// ---------------- flash rel-pos attention (v9: 8 waves x 16 rows, 512 threads) ----------
__global__ __launch_bounds__(512, 4) void attn_k(
    const u16* __restrict__ q, const u16* __restrict__ k, const u16* __restrict__ vtg,
    const u16* __restrict__ p, const float* __restrict__ pbu, const float* __restrict__ pbv,
    const int* __restrict__ xlens, u16* __restrict__ ao)
{
    __shared__ u16 Ks[2][64 * 64];
    __shared__ u16 Vt[64 * 64];
    __shared__ u16 Ps[256 * 64];
    __shared__ u16 Tb[8][16 * 72];

    int tid = threadIdx.x, l = tid & 63, wid = tid >> 6;   // wid 0..7
    int r = l & 15, g = l >> 4, kq = g << 3;
    int t0 = blockIdx.x << 7;
    int bh = blockIdx.y, b = bh & 7, h = bh >> 3;
    int tw = t0 + wid * 16;
    int xlen = xlens[b];
    const u16* qh = q + (size_t)(b * 8 + h) * 65536;
    const u16* kh = k + (size_t)(b * 8 + h) * 65536;
    const u16* vh = vtg + (size_t)(b * 8 + h) * 65536;
    const u16* ph = p + (size_t)h * 2047 * 64;

    int rw8 = l >> 3;
    int csw = ((l & 7) ^ rw8) << 3;            // pre-swizzled source col (elems)
    int off0 = ((g ^ (r & 7)) << 3);           // swizzled read col, blk g
    int off1 = (((4 + g) ^ (r & 7)) << 3);     // blk 4+g

    const float SCALE = 0.18033688f;           // 0.125 / ln(2)

    // Q frags (+pos biases, prescaled)
    s8v qu[2], qv[2];
    #pragma unroll
    for (int ks = 0; ks < 2; ++ks) {
        union { s8v v; u16 u[8]; } src, du, dv;
        src.v = *(const s8v*)&qh[(tw + r) * 64 + ks * 32 + kq];
        float4 u0 = *(const float4*)&pbu[h * 64 + ks * 32 + kq];
        float4 u1 = *(const float4*)&pbu[h * 64 + ks * 32 + kq + 4];
        float4 v0 = *(const float4*)&pbv[h * 64 + ks * 32 + kq];
        float4 v1 = *(const float4*)&pbv[h * 64 + ks * 32 + kq + 4];
        float ub[8] = {u0.x, u0.y, u0.z, u0.w, u1.x, u1.y, u1.z, u1.w};
        float vb_[8] = {v0.x, v0.y, v0.z, v0.w, v1.x, v1.y, v1.z, v1.w};
        #pragma unroll
        for (int e = 0; e < 8; ++e) {
            float qf = bf2f(src.u[e]);
            du.u[e] = f2bf((qf + ub[e]) * SCALE);
            dv.u[e] = f2bf((qf + vb_[e]) * SCALE);
        }
        qu[ks] = du.v; qv[ks] = dv.v;
    }

    int B0 = 896 - t0;                          // lowest p-row this block touches
    int nst = (xlen + 63) >> 6;

    // ---- prologue: K0, V0 (1 gld/wave), P rows [B0, B0+192) (3 gld/wave) ----
    {
        int rowb = wid * 8;
        gld16(&kh[(rowb + rw8) * 64 + csw], &Ks[0][rowb * 64]);
        gld16(&vh[(rowb + rw8) * 1024 + csw], &Vt[rowb * 64]);
    }
    #pragma unroll
    for (int it = 0; it < 3; ++it) {
        int row = wid * 24 + it * 8;
        int slot = (B0 + row) & 255;
        gld16(&ph[(size_t)(B0 + row + rw8) * 64 + csw], &Ps[slot * 64]);
    }
    __syncthreads();

    float lst[4] = {0.f, 0.f, 0.f, 0.f};
    f4v zero = {0.f, 0.f, 0.f, 0.f};
    f4v o[4] = {zero, zero, zero, zero};
    u16* tb = &Tb[wid][0];

    for (int i = 0; i < nst; ++i) {
        int cur = i & 1, s0 = i << 6;
        // ---- issue V(i) ----
        if (i > 0) {
            int rowb = wid * 8;
            gld16(&vh[(rowb + rw8) * 1024 + s0 + csw], &Vt[rowb * 64]);
        }
        // ---- prefetch K(i+1), P(+64) ----
        if (i + 1 < nst) {
            int s1 = s0 + 64;
            int rowb = wid * 8;
            gld16(&kh[(s1 + rowb + rw8) * 64 + csw], &Ks[cur ^ 1][rowb * 64]);
            int chunk = B0 + 192 + s0 + wid * 8;
            int slot = chunk & 255;
            int gp = chunk + rw8; gp = gp > 2046 ? 2046 : gp;
            gld16(&ph[(size_t)gp * 64 + csw], &Ps[slot * 64]);
        }
        // ---- QK: 8 MFMAs ----
        const u16* KB = &Ks[cur][0];
        f4v st4[4];
        __builtin_amdgcn_s_setprio(1);
        #pragma unroll
        for (int nf = 0; nf < 4; ++nf) {
            int row = (nf * 16 + r) * 64;
            s8v k0 = *(const s8v*)&KB[row + off0];
            s8v k1 = *(const s8v*)&KB[row + off1];
            st4[nf] = MFMA(qu[1], k1, MFMA(qu[0], k0, zero));
        }
        // ---- band: 10 MFMAs ----
        int pstart = 1008 + s0 - tw;
        f4v bst[5];
        #pragma unroll
        for (int pf = 0; pf < 5; ++pf) {
            int slot = (pstart + pf * 16 + r) & 255;
            const u16* rowp = &Ps[slot * 64];
            f4v a = MFMA(qv[0], *(const s8v*)&rowp[off0], zero);
            bst[pf] = MFMA(qv[1], *(const s8v*)&rowp[off1], a);
        }
        __builtin_amdgcn_s_setprio(0);
        bool full = (s0 + 64 <= xlen);
        // ---- packed 3-bperm rel-shift gather + exp2 ----
        float pr[4][4];
        #pragma unroll
        for (int j = 0; j < 4; ++j) {
            int tl = g * 4 + j;
            int d = r + 15 - tl;                       // 0..30
            int al = ((g << 4) | (d & 15)) << 2;
            unsigned w0 = (unsigned)f2bt(bst[0][j]) | ((unsigned)f2bt(bst[1][j]) << 16);
            unsigned w1 = (unsigned)f2bt(bst[2][j]) | ((unsigned)f2bt(bst[3][j]) << 16);
            unsigned w2 = (unsigned)f2bt(bst[4][j]);
            unsigned p0 = (unsigned)__builtin_amdgcn_ds_bpermute(al, (int)w0);
            unsigned p1 = (unsigned)__builtin_amdgcn_ds_bpermute(al, (int)w1);
            unsigned p2 = (unsigned)__builtin_amdgcn_ds_bpermute(al, (int)w2);
            bool lo = d < 16;
            float bds[4];
            bds[0] = bf2f((u16)(lo ? (p0 & 0xffffu) : (p0 >> 16)));
            bds[1] = bf2f((u16)(lo ? (p0 >> 16) : (p1 & 0xffffu)));
            bds[2] = bf2f((u16)(lo ? (p1 & 0xffffu) : (p1 >> 16)));
            bds[3] = bf2f((u16)(lo ? (p1 >> 16) : (p2 & 0xffffu)));
            #pragma unroll
            for (int nf = 0; nf < 4; ++nf) {
                float e = exp2f(st4[nf][j] + bds[nf]);
                if (!full) e = (s0 + nf * 16 + r >= xlen) ? 0.f : e;
                pr[nf][j] = e;
            }
        }
        #pragma unroll
        for (int j = 0; j < 4; ++j)
            lst[j] += (pr[0][j] + pr[1][j]) + (pr[2][j] + pr[3][j]);
        // ---- P -> per-wave LDS A-tile, read back frags ----
        #pragma unroll
        for (int nf = 0; nf < 4; ++nf)
            #pragma unroll
            for (int j = 0; j < 4; ++j)
                tb[(g * 4 + j) * 72 + nf * 16 + r] = f2bt(pr[nf][j]);
        asm volatile("s_waitcnt lgkmcnt(0)" ::: "memory");
        __builtin_amdgcn_sched_barrier(0);
        s8v pa0 = *(const s8v*)&tb[r * 72 + kq];
        s8v pa1 = *(const s8v*)&tb[r * 72 + 32 + kq];
        // ---- wait V (counted: keep K/P prefetch in flight) ----
        if (i > 0) {
            if (i + 1 < nst) asm volatile("s_waitcnt vmcnt(2)" ::: "memory");
            else             asm volatile("s_waitcnt vmcnt(0)" ::: "memory");
        }
        // ---- PV: 8 MFMAs ----
        __builtin_amdgcn_s_setprio(1);
        #pragma unroll
        for (int i2 = 0; i2 < 4; ++i2) {
            int vrow = (i2 * 16 + r) * 64;
            o[i2] = MFMA(pa0, *(const s8v*)&Vt[vrow + off0], o[i2]);
            o[i2] = MFMA(pa1, *(const s8v*)&Vt[vrow + off1], o[i2]);
        }
        __builtin_amdgcn_s_setprio(0);
        __syncthreads();
    }
    // ---- final l reduce + normalize + write ----
    #pragma unroll
    for (int j = 0; j < 4; ++j) {
        float rs = lst[j];
        rs += __shfl_xor(rs, 1); rs += __shfl_xor(rs, 2);
        rs += __shfl_xor(rs, 4); rs += __shfl_xor(rs, 8);
        float inv = 1.f / rs;
        int t = tw + g * 4 + j;
        #pragma unroll
        for (int i2 = 0; i2 < 4; ++i2)
            ao[((size_t)(b * 1024 + t)) * 512 + h * 64 + i2 * 16 + r] = f2bf(o[i2][j] * inv);
    }
}

// ---------------- launch ----------------
extern "C" void kernel_launch(void* const* d_in, const int* in_sizes, int n_in,
                              void* d_out, int out_size, void* d_ws, size_t ws_size,
                              hipStream_t stream)
{
    (void)in_sizes; (void)n_in; (void)out_size; (void)ws_size;
    const float* x     = (const float*)d_in[0];
    const int*   xlens = (const int*)d_in[1];
    const float* pos_e = (const float*)d_in[2];
    const float* gam   = (const float*)d_in[3];
    const float* bet   = (const float*)d_in[4];
    const float* Wq    = (const float*)d_in[5];
    const float* bq    = (const float*)d_in[6];
    const float* Wk    = (const float*)d_in[7];
    const float* bk    = (const float*)d_in[8];
    const float* Wv    = (const float*)d_in[9];
    const float* bv    = (const float*)d_in[10];
    const float* Wpos  = (const float*)d_in[11];
    const float* pbu   = (const float*)d_in[12];
    const float* pbv   = (const float*)d_in[13];
    const float* Wo    = (const float*)d_in[14];
    const float* bo    = (const float*)d_in[15];
    float* out = (float*)d_out;

    char* ws = (char*)d_ws;
    u16* xn  = (u16*)(ws);                    // LN out, later attn out
    u16* qb  = (u16*)(ws + 8388608);          // (B,H,T,DK)
    u16* kb  = (u16*)(ws + 16777216);         // (B,H,T,DK)
    u16* vtg = (u16*)(ws + 25165824);         // (B,H,DK,T) transposed
    u16* pbf = (u16*)(ws + 33554432);         // (H,2047,DK)
    u16* pe  = (u16*)(ws + 35651584);         // pos_emb bf16, 2048 rows
    u16* wt  = (u16*)(ws + 37748736);         // 5 x 512x512 W^T bf16

    prep_k<<<4353, 256, 0, stream>>>(Wq, Wk, Wv, Wpos, Wo, pos_e, xlens,
                                     x, gam, bet, wt, pe,
                                     out + (size_t)8192 * 512, xn);
    gemm_k<<<dim3(64, 13), 256, 0, stream>>>(xn, pe, wt, bq, bk, bv, 0,
                                             qb, kb, vtg, pbf, nullptr);
    attn_k<<<dim3(8, 64), 512, 0, stream>>>(qb, kb, vtg, pbf, pbu, pbv, xlens, xn);
    gemm_k<<<dim3(64, 4), 256, 0, stream>>>(xn, nullptr, wt, bo, nullptr, nullptr, 2,
                                            nullptr, nullptr, nullptr, nullptr, out);
}

// Round 13
// 98.469 us; speedup vs baseline: 1.1016x; 1.0348x over previous
//
#include <hip/hip_runtime.h>
#include <stdint.h>

// ConformerSelfAttention (B=8,T=1024,D=512,H=8,DK=64) for gfx950. Round 13.
// R12/R9 body + xlen-balanced block schedule: blocks l and l+256 (same CU by
// XCD round-robin fill) get complementary-rank batches -> per-CU work ~2*mean.

typedef __attribute__((ext_vector_type(8))) short s8v;
typedef __attribute__((ext_vector_type(4))) short s4v;
typedef __attribute__((ext_vector_type(4))) float f4v;
typedef unsigned short u16;

#define MFMA(a, b, c) __builtin_amdgcn_mfma_f32_16x16x32_bf16((a), (b), (c), 0, 0, 0)

__device__ __forceinline__ float bf2f(u16 u) {
    union { unsigned i; float f; } w; w.i = ((unsigned)u) << 16; return w.f;
}
__device__ __forceinline__ u16 f2bf(float f) {   // RTNE (outputs)
    union { float f; unsigned i; } w; w.f = f;
    return (u16)((w.i + 0x7FFFu + ((w.i >> 16) & 1u)) >> 16);
}
__device__ __forceinline__ u16 f2bt(float f) {   // trunc (intermediates)
    union { float f; unsigned i; } w; w.f = f;
    return (u16)(w.i >> 16);
}
__device__ __forceinline__ void gld16(const void* g, void* l) {
    __builtin_amdgcn_global_load_lds(
        (const __attribute__((address_space(1))) unsigned int*)g,
        (__attribute__((address_space(3))) unsigned int*)l, 16, 0, 0);
}

// ------------- prep (W^T->bf16, pos_emb->bf16, xlens tail) + LayerNorm, merged -------------
__global__ __launch_bounds__(256) void prep_k(
    const float* __restrict__ Wq, const float* __restrict__ Wk, const float* __restrict__ Wv,
    const float* __restrict__ Wpos, const float* __restrict__ Wo,
    const float* __restrict__ pos_emb, const int* __restrict__ xlens,
    const float* __restrict__ x, const float* __restrict__ gamma,
    const float* __restrict__ beta,
    u16* __restrict__ wt, u16* __restrict__ pe, float* __restrict__ tail,
    u16* __restrict__ xn)
{
    int bid = blockIdx.x, tid = threadIdx.x;
    if (bid < 1280) {
        __shared__ float lt[32][33];
        int mat = bid >> 8, tile = bid & 255;
        int kt = (tile >> 4) << 5, nt = (tile & 15) << 5;
        const float* W = mat == 0 ? Wq : mat == 1 ? Wk : mat == 2 ? Wv : mat == 3 ? Wpos : Wo;
        int ty = tid >> 3, tx = tid & 7;
        float4 vv = *(const float4*)&W[(kt + ty) * 512 + nt + tx * 4];
        lt[ty][tx * 4 + 0] = vv.x; lt[ty][tx * 4 + 1] = vv.y;
        lt[ty][tx * 4 + 2] = vv.z; lt[ty][tx * 4 + 3] = vv.w;
        __syncthreads();
        int nl = tid >> 3, k4 = (tid & 7) * 4;
        union { s4v v; u16 u[4]; } ob;
        #pragma unroll
        for (int e = 0; e < 4; ++e) ob.u[e] = f2bf(lt[k4 + e][nl]);
        *(s4v*)&wt[mat * 262144 + (nt + nl) * 512 + kt + k4] = ob.v;
    } else if (bid < 2304) {
        int i = (bid - 1280) * 1024 + tid * 4;
        union { s4v v; u16 u[4]; } ob;
        if (i < 2047 * 512) {
            float4 vv = *(const float4*)&pos_emb[i];
            ob.u[0] = f2bf(vv.x); ob.u[1] = f2bf(vv.y);
            ob.u[2] = f2bf(vv.z); ob.u[3] = f2bf(vv.w);
        } else {
            ob.u[0] = ob.u[1] = ob.u[2] = ob.u[3] = 0;
        }
        *(s4v*)&pe[i] = ob.v;
    } else if (bid == 2304) {
        if (tid < 8) tail[tid] = (float)xlens[tid];
    } else {
        int tok = (bid - 2305) * 4 + (tid >> 6);
        int l = tid & 63;
        const float* xr = x + (size_t)tok * 512 + l * 8;
        float v[8];
        {
            float4 a = *(const float4*)xr; float4 b = *(const float4*)(xr + 4);
            v[0] = a.x; v[1] = a.y; v[2] = a.z; v[3] = a.w;
            v[4] = b.x; v[5] = b.y; v[6] = b.z; v[7] = b.w;
        }
        float s = 0.f, q = 0.f;
        #pragma unroll
        for (int e = 0; e < 8; ++e) { s += v[e]; q += v[e] * v[e]; }
        #pragma unroll
        for (int off = 1; off < 64; off <<= 1) { s += __shfl_xor(s, off); q += __shfl_xor(q, off); }
        float mean = s * (1.f / 512.f);
        float var = q * (1.f / 512.f) - mean * mean;
        float inv = rsqrtf(var + 1e-5f);
        union { s8v v; u16 u[8]; } ob;
        #pragma unroll
        for (int e = 0; e < 8; ++e)
            ob.u[e] = f2bf((v[e] - mean) * inv * gamma[l * 8 + e] + beta[l * 8 + e]);
        *(s8v*)&xn[(size_t)tok * 512 + l * 8] = ob.v;
    }
}

// ---------------- GEMM v2: 128x128 tile, BK=64, stage-ahead dbuf, swizzled LDS ----------
__global__ __launch_bounds__(256, 2) void gemm_k(
    const u16* __restrict__ A, const u16* __restrict__ Ap, const u16* __restrict__ wt,
    const float* __restrict__ bq, const float* __restrict__ bk, const float* __restrict__ bv,
    int mode, u16* __restrict__ qo, u16* __restrict__ ko, u16* __restrict__ vtg,
    u16* __restrict__ pb, float* __restrict__ of)
{
    __shared__ u16 Al[2][128 * 64];
    __shared__ u16 Bl[2][128 * 64];
    int tid = threadIdx.x, l = tid & 63, wid = tid >> 6;
    int wr = wid >> 1, wc = wid & 1, r = l & 15, g = l >> 4;
    int m0, nb, mat;
    const u16 *Ag, *Wg;
    if (mode == 0) {
        if (blockIdx.y < 12) {
            m0 = blockIdx.x << 7; int n0 = blockIdx.y << 7;
            mat = n0 >> 9; nb = n0 & 511; Ag = A; Wg = wt + mat * 262144;
        } else {
            mat = 3; m0 = (blockIdx.x & 15) << 7; nb = (blockIdx.x >> 4) << 7;
            Ag = Ap; Wg = wt + 3 * 262144;
        }
    } else {
        mat = 4; m0 = blockIdx.x << 7; nb = blockIdx.y << 7; Ag = A; Wg = wt + 4 * 262144;
    }

    int rw8 = l >> 3;
    int csw = ((l & 7) ^ rw8) << 3;
    int off0 = ((g ^ (r & 7)) << 3);
    int off1 = (((4 + g) ^ (r & 7)) << 3);

    f4v zero = {0.f, 0.f, 0.f, 0.f};
    f4v acc[4][4];
    #pragma unroll
    for (int i = 0; i < 4; ++i)
        #pragma unroll
        for (int j = 0; j < 4; ++j) acc[i][j] = zero;

    #pragma unroll
    for (int it = 0; it < 4; ++it) {
        int rowb = wid * 32 + it * 8;
        gld16(&Ag[(size_t)(m0 + rowb + rw8) * 512 + csw], &Al[0][rowb * 64]);
        gld16(&Wg[(size_t)(nb + rowb + rw8) * 512 + csw], &Bl[0][rowb * 64]);
    }
    __syncthreads();

    for (int t = 0; t < 8; ++t) {
        int cur = t & 1;
        if (t < 7) {
            int k1 = (t + 1) << 6;
            #pragma unroll
            for (int it = 0; it < 4; ++it) {
                int rowb = wid * 32 + it * 8;
                gld16(&Ag[(size_t)(m0 + rowb + rw8) * 512 + k1 + csw], &Al[cur ^ 1][rowb * 64]);
                gld16(&Wg[(size_t)(nb + rowb + rw8) * 512 + k1 + csw], &Bl[cur ^ 1][rowb * 64]);
            }
        }
        s8v af[4][2], bfv[4][2];
        #pragma unroll
        for (int i = 0; i < 4; ++i) {
            int row = (wr * 64 + i * 16 + r) * 64;
            af[i][0] = *(const s8v*)&Al[cur][row + off0];
            af[i][1] = *(const s8v*)&Al[cur][row + off1];
        }
        #pragma unroll
        for (int j = 0; j < 4; ++j) {
            int row = (wc * 64 + j * 16 + r) * 64;
            bfv[j][0] = *(const s8v*)&Bl[cur][row + off0];
            bfv[j][1] = *(const s8v*)&Bl[cur][row + off1];
        }
        __builtin_amdgcn_s_setprio(1);
        #pragma unroll
        for (int i = 0; i < 4; ++i)
            #pragma unroll
            for (int j = 0; j < 4; ++j) {
                acc[i][j] = MFMA(af[i][0], bfv[j][0], acc[i][j]);
                acc[i][j] = MFMA(af[i][1], bfv[j][1], acc[i][j]);
            }
        __builtin_amdgcn_s_setprio(0);
        __syncthreads();
    }

    #pragma unroll
    for (int i = 0; i < 4; ++i)
        #pragma unroll
        for (int j = 0; j < 4; ++j) {
            int ncol = nb + wc * 64 + j * 16 + r;
            int mbase = m0 + wr * 64 + i * 16 + g * 4;
            if (mode == 2) {
                float bb = bq[ncol];
                #pragma unroll
                for (int jj = 0; jj < 4; ++jj)
                    of[(size_t)(mbase + jj) * 512 + ncol] = acc[i][j][jj] + bb;
            } else if (mat == 3) {
                int hh = ncol >> 6, dk = ncol & 63;
                #pragma unroll
                for (int jj = 0; jj < 4; ++jj) {
                    int m = mbase + jj;
                    if (m < 2047) pb[(hh * 2047 + m) * 64 + dk] = f2bf(acc[i][j][jj]);
                }
            } else if (mat == 2) {
                float bb = bv[ncol];
                int hh = ncol >> 6, dk = ncol & 63;
                int bbx = mbase >> 10, t = mbase & 1023;
                union { s4v v; u16 u[4]; } pk;
                #pragma unroll
                for (int jj = 0; jj < 4; ++jj) pk.u[jj] = f2bf(acc[i][j][jj] + bb);
                *(s4v*)&vtg[((size_t)(bbx * 8 + hh) * 64 + dk) * 1024 + t] = pk.v;
            } else {
                float bb = (mat == 0 ? bq : bk)[ncol];
                u16* dst = (mat == 0) ? qo : ko;
                int hh = ncol >> 6, dk = ncol & 63;
                #pragma unroll
                for (int jj = 0; jj < 4; ++jj) {
                    int m = mbase + jj;
                    int bbx = m >> 10, t = m & 1023;
                    dst[((size_t)(bbx * 8 + hh) * 1024 + t) * 64 + dk] = f2bf(acc[i][j][jj] + bb);
                }
            }
        }
}

// ---------------- flash rel-pos attention (v13: R9 body + balanced schedule) ----------
// grid(512): block l and l+256 land on the same CU (XCD round-robin, 2 slots);
// give them complementary xlen-ranks so per-CU work ~= 2*mean, not 2*max.
__global__ __launch_bounds__(512, 4) void attn_k(
    const u16* __restrict__ q, const u16* __restrict__ k, const u16* __restrict__ vtg,
    const u16* __restrict__ p, const float* __restrict__ pbu, const float* __restrict__ pbv,
    const int* __restrict__ xlens, u16* __restrict__ ao)
{
    __shared__ u16 Ks[2][64 * 64];
    __shared__ u16 Vt[64 * 64];
    __shared__ u16 Ps[256 * 64];
    __shared__ u16 Tb[8][16 * 72];

    int tid = threadIdx.x, l = tid & 63, wid = tid >> 6;   // wid 0..7
    int r = l & 15, g = l >> 4, kq = g << 3;

    // ---- balanced (b,h,t-tile) assignment from xlen ranks ----
    int l8[8];
    #pragma unroll
    for (int e = 0; e < 8; ++e) l8[e] = xlens[e];
    int ell = blockIdx.x;
    int slot = ell >> 8, m = ell & 255;
    int kr = m >> 6; if (slot) kr = 7 - kr;        // complementary rank for slot 1
    int b = 0;
    #pragma unroll
    for (int e = 0; e < 8; ++e) {
        int rk = 0;
        #pragma unroll
        for (int j = 0; j < 8; ++j)
            rk += (l8[j] > l8[e]) || (l8[j] == l8[e] && j < e);
        if (rk == kr) b = e;
    }
    int rem = m & 63;
    int h = rem >> 3;
    int t0 = (rem & 7) << 7;
    int tw = t0 + wid * 16;
    int xlen = l8[b];

    const u16* qh = q + (size_t)(b * 8 + h) * 65536;
    const u16* kh = k + (size_t)(b * 8 + h) * 65536;
    const u16* vh = vtg + (size_t)(b * 8 + h) * 65536;
    const u16* ph = p + (size_t)h * 2047 * 64;

    int rw8 = l >> 3;
    int csw = ((l & 7) ^ rw8) << 3;            // pre-swizzled source col (elems)
    int off0 = ((g ^ (r & 7)) << 3);           // swizzled read col, blk g
    int off1 = (((4 + g) ^ (r & 7)) << 3);     // blk 4+g

    const float SCALE = 0.18033688f;           // 0.125 / ln(2)

    // Q frags (+pos biases, prescaled)
    s8v qu[2], qv[2];
    #pragma unroll
    for (int ks = 0; ks < 2; ++ks) {
        union { s8v v; u16 u[8]; } src, du, dv;
        src.v = *(const s8v*)&qh[(tw + r) * 64 + ks * 32 + kq];
        float4 u0 = *(const float4*)&pbu[h * 64 + ks * 32 + kq];
        float4 u1 = *(const float4*)&pbu[h * 64 + ks * 32 + kq + 4];
        float4 v0 = *(const float4*)&pbv[h * 64 + ks * 32 + kq];
        float4 v1 = *(const float4*)&pbv[h * 64 + ks * 32 + kq + 4];
        float ub[8] = {u0.x, u0.y, u0.z, u0.w, u1.x, u1.y, u1.z, u1.w};
        float vb_[8] = {v0.x, v0.y, v0.z, v0.w, v1.x, v1.y, v1.z, v1.w};
        #pragma unroll
        for (int e = 0; e < 8; ++e) {
            float qf = bf2f(src.u[e]);
            du.u[e] = f2bf((qf + ub[e]) * SCALE);
            dv.u[e] = f2bf((qf + vb_[e]) * SCALE);
        }
        qu[ks] = du.v; qv[ks] = dv.v;
    }

    int B0 = 896 - t0;                          // lowest p-row this block touches
    int nst = (xlen + 63) >> 6;

    // ---- prologue: K0, V0 (1 gld/wave), P rows [B0, B0+192) (3 gld/wave) ----
    {
        int rowb = wid * 8;
        gld16(&kh[(rowb + rw8) * 64 + csw], &Ks[0][rowb * 64]);
        gld16(&vh[(rowb + rw8) * 1024 + csw], &Vt[rowb * 64]);
    }
    #pragma unroll
    for (int it = 0; it < 3; ++it) {
        int row = wid * 24 + it * 8;
        int slot2 = (B0 + row) & 255;
        gld16(&ph[(size_t)(B0 + row + rw8) * 64 + csw], &Ps[slot2 * 64]);
    }
    __syncthreads();

    float lst[4] = {0.f, 0.f, 0.f, 0.f};
    f4v zero = {0.f, 0.f, 0.f, 0.f};
    f4v o[4] = {zero, zero, zero, zero};
    u16* tb = &Tb[wid][0];

    for (int i = 0; i < nst; ++i) {
        int cur = i & 1, s0 = i << 6;
        // ---- issue V(i) ----
        if (i > 0) {
            int rowb = wid * 8;
            gld16(&vh[(rowb + rw8) * 1024 + s0 + csw], &Vt[rowb * 64]);
        }
        // ---- prefetch K(i+1), P(+64) ----
        if (i + 1 < nst) {
            int s1 = s0 + 64;
            int rowb = wid * 8;
            gld16(&kh[(s1 + rowb + rw8) * 64 + csw], &Ks[cur ^ 1][rowb * 64]);
            int chunk = B0 + 192 + s0 + wid * 8;
            int slot2 = chunk & 255;
            int gp = chunk + rw8; gp = gp > 2046 ? 2046 : gp;
            gld16(&ph[(size_t)gp * 64 + csw], &Ps[slot2 * 64]);
        }
        // ---- QK: 8 MFMAs ----
        const u16* KB = &Ks[cur][0];
        f4v st4[4];
        __builtin_amdgcn_s_setprio(1);
        #pragma unroll
        for (int nf = 0; nf < 4; ++nf) {
            int row = (nf * 16 + r) * 64;
            s8v k0 = *(const s8v*)&KB[row + off0];
            s8v k1 = *(const s8v*)&KB[row + off1];
            st4[nf] = MFMA(qu[1], k1, MFMA(qu[0], k0, zero));
        }
        // ---- band: 10 MFMAs ----
        int pstart = 1008 + s0 - tw;
        f4v bst[5];
        #pragma unroll
        for (int pf = 0; pf < 5; ++pf) {
            int slot2 = (pstart + pf * 16 + r) & 255;
            const u16* rowp = &Ps[slot2 * 64];
            f4v a = MFMA(qv[0], *(const s8v*)&rowp[off0], zero);
            bst[pf] = MFMA(qv[1], *(const s8v*)&rowp[off1], a);
        }
        __builtin_amdgcn_s_setprio(0);
        bool full = (s0 + 64 <= xlen);
        // ---- packed 3-bperm rel-shift gather + exp2 ----
        float pr[4][4];
        #pragma unroll
        for (int j = 0; j < 4; ++j) {
            int tl = g * 4 + j;
            int d = r + 15 - tl;                       // 0..30
            int al = ((g << 4) | (d & 15)) << 2;
            unsigned w0 = (unsigned)f2bt(bst[0][j]) | ((unsigned)f2bt(bst[1][j]) << 16);
            unsigned w1 = (unsigned)f2bt(bst[2][j]) | ((unsigned)f2bt(bst[3][j]) << 16);
            unsigned w2 = (unsigned)f2bt(bst[4][j]);
            unsigned p0 = (unsigned)__builtin_amdgcn_ds_bpermute(al, (int)w0);
            unsigned p1 = (unsigned)__builtin_amdgcn_ds_bpermute(al, (int)w1);
            unsigned p2 = (unsigned)__builtin_amdgcn_ds_bpermute(al, (int)w2);
            bool lo = d < 16;
            float bds[4];
            bds[0] = bf2f((u16)(lo ? (p0 & 0xffffu) : (p0 >> 16)));
            bds[1] = bf2f((u16)(lo ? (p0 >> 16) : (p1 & 0xffffu)));
            bds[2] = bf2f((u16)(lo ? (p1 & 0xffffu) : (p1 >> 16)));
            bds[3] = bf2f((u16)(lo ? (p1 >> 16) : (p2 & 0xffffu)));
            #pragma unroll
            for (int nf = 0; nf < 4; ++nf) {
                float e = exp2f(st4[nf][j] + bds[nf]);
                if (!full) e = (s0 + nf * 16 + r >= xlen) ? 0.f : e;
                pr[nf][j] = e;
            }
        }
        #pragma unroll
        for (int j = 0; j < 4; ++j)
            lst[j] += (pr[0][j] + pr[1][j]) + (pr[2][j] + pr[3][j]);
        // ---- P -> per-wave LDS A-tile, read back frags ----
        #pragma unroll
        for (int nf = 0; nf < 4; ++nf)
            #pragma unroll
            for (int j = 0; j < 4; ++j)
                tb[(g * 4 + j) * 72 + nf * 16 + r] = f2bt(pr[nf][j]);
        asm volatile("s_waitcnt lgkmcnt(0)" ::: "memory");
        __builtin_amdgcn_sched_barrier(0);
        s8v pa0 = *(const s8v*)&tb[r * 72 + kq];
        s8v pa1 = *(const s8v*)&tb[r * 72 + 32 + kq];
        // ---- wait V (counted: keep K/P prefetch in flight) ----
        if (i > 0) {
            if (i + 1 < nst) asm volatile("s_waitcnt vmcnt(2)" ::: "memory");
            else             asm volatile("s_waitcnt vmcnt(0)" ::: "memory");
        }
        // ---- PV: 8 MFMAs ----
        __builtin_amdgcn_s_setprio(1);
        #pragma unroll
        for (int i2 = 0; i2 < 4; ++i2) {
            int vrow = (i2 * 16 + r) * 64;
            o[i2] = MFMA(pa0, *(const s8v*)&Vt[vrow + off0], o[i2]);
            o[i2] = MFMA(pa1, *(const s8v*)&Vt[vrow + off1], o[i2]);
        }
        __builtin_amdgcn_s_setprio(0);
        __syncthreads();
    }
    // ---- final l reduce + normalize + write ----
    #pragma unroll
    for (int j = 0; j < 4; ++j) {
        float rs = lst[j];
        rs += __shfl_xor(rs, 1); rs += __shfl_xor(rs, 2);
        rs += __shfl_xor(rs, 4); rs += __shfl_xor(rs, 8);
        float inv = 1.f / rs;
        int t = tw + g * 4 + j;
        #pragma unroll
        for (int i2 = 0; i2 < 4; ++i2)
            ao[((size_t)(b * 1024 + t)) * 512 + h * 64 + i2 * 16 + r] = f2bf(o[i2][j] * inv);
    }
}

// ---------------- launch ----------------
extern "C" void kernel_launch(void* const* d_in, const int* in_sizes, int n_in,
                              void* d_out, int out_size, void* d_ws, size_t ws_size,
                              hipStream_t stream)
{
    (void)in_sizes; (void)n_in; (void)out_size; (void)ws_size;
    const float* x     = (const float*)d_in[0];
    const int*   xlens = (const int*)d_in[1];
    const float* pos_e = (const float*)d_in[2];
    const float* gam   = (const float*)d_in[3];
    const float* bet   = (const float*)d_in[4];
    const float* Wq    = (const float*)d_in[5];
    const float* bq    = (const float*)d_in[6];
    const float* Wk    = (const float*)d_in[7];
    const float* bk    = (const float*)d_in[8];
    const float* Wv    = (const float*)d_in[9];
    const float* bv    = (const float*)d_in[10];
    const float* Wpos  = (const float*)d_in[11];
    const float* pbu   = (const float*)d_in[12];
    const float* pbv   = (const float*)d_in[13];
    const float* Wo    = (const float*)d_in[14];
    const float* bo    = (const float*)d_in[15];
    float* out = (float*)d_out;

    char* ws = (char*)d_ws;
    u16* xn  = (u16*)(ws);                    // LN out, later attn out
    u16* qb  = (u16*)(ws + 8388608);          // (B,H,T,DK)
    u16* kb  = (u16*)(ws + 16777216);         // (B,H,T,DK)
    u16* vtg = (u16*)(ws + 25165824);         // (B,H,DK,T) transposed
    u16* pbf = (u16*)(ws + 33554432);         // (H,2047,DK)
    u16* pe  = (u16*)(ws + 35651584);         // pos_emb bf16, 2048 rows
    u16* wt  = (u16*)(ws + 37748736);         // 5 x 512x512 W^T bf16

    prep_k<<<4353, 256, 0, stream>>>(Wq, Wk, Wv, Wpos, Wo, pos_e, xlens,
                                     x, gam, bet, wt, pe,
                                     out + (size_t)8192 * 512, xn);
    gemm_k<<<dim3(64, 13), 256, 0, stream>>>(xn, pe, wt, bq, bk, bv, 0,
                                             qb, kb, vtg, pbf, nullptr);
    attn_k<<<dim3(512), 512, 0, stream>>>(qb, kb, vtg, pbf, pbu, pbv, xlens, xn);
    gemm_k<<<dim3(64, 4), 256, 0, stream>>>(xn, nullptr, wt, bo, nullptr, nullptr, 2,
                                            nullptr, nullptr, nullptr, nullptr, out);
}